// Round 11
// baseline (80.753 us; speedup 1.0000x reference)
//
#include <hip/hip_runtime.h>

// MSDeformAttn — round 10: R9 structure with the VGPR strangulation fixed
// (no min-wave launch bound) and ofa_s bank-conflict padding. 3 launches.
#define NB 2
#define NQ 10000
#define DM 256
#define NHEADS 8
#define NLEV 4
#define NPTS 4
#define DHEAD 32
#define LEN_IN 5440   // 64*64 + 32*32 + 16*16 + 8*8
#define OFA_PAD 392   // 384 + 8: row stride 784 B == 4 banks mod 32

typedef _Float16 f16x8 __attribute__((ext_vector_type(8)));
typedef _Float16 f16x4 __attribute__((ext_vector_type(4)));
typedef float    f32x4 __attribute__((ext_vector_type(4)));
typedef unsigned short u16x4 __attribute__((ext_vector_type(4)));

union TaskU {
    struct { f16x4 w; u16x4 p; } s;
    uint4 u;
};

// ---------------- prep: weight swizzle + fp32->fp16 cvt of inflat ----------
__device__ __forceinline__ void swz_one(const float* __restrict__ W, int Nw,
                                        int srcCol, int kbase,
                                        _Float16* __restrict__ dst) {
    f16x8 v;
    #pragma unroll
    for (int j = 0; j < 8; ++j) v[j] = (_Float16)W[(size_t)(kbase + j) * Nw + srcCol];
    *(f16x8*)dst = v;
}

__global__ __launch_bounds__(256) void prep(const float* __restrict__ Wv,
                                            const float* __restrict__ Wo,
                                            const float* __restrict__ Wa,
                                            const float* __restrict__ Wout,
                                            const float* __restrict__ inflat,
                                            _Float16* __restrict__ Wv_swz,
                                            _Float16* __restrict__ Wofa_swz,
                                            _Float16* __restrict__ Wout_swz,
                                            _Float16* __restrict__ inflat_h) {
    const int b = blockIdx.x;
    const int t = threadIdx.x;
    if (b < 112) {
        const int tid = b * 256 + t;
        if (tid < 8192) {
            const int lane = tid & 63, tt = tid >> 6, kt = tt & 7, nt = tt >> 3;
            swz_one(Wv, 256, nt * 16 + (lane & 15), kt * 32 + (lane >> 4) * 8,
                    Wv_swz + ((size_t)(nt * 8 + kt) * 64 + lane) * 8);
        } else if (tid < 16384) {
            const int local = tid - 8192;
            const int lane = local & 63, tt = local >> 6, kt = tt & 7, nt = tt >> 3;
            swz_one(Wo, 256, nt * 16 + (lane & 15), kt * 32 + (lane >> 4) * 8,
                    Wofa_swz + ((size_t)(nt * 8 + kt) * 64 + lane) * 8);
        } else if (tid < 20480) {
            const int local = tid - 16384;
            const int lane = local & 63, tt = local >> 6, kt = tt & 7, nt = tt >> 3;
            swz_one(Wa, 128, nt * 16 + (lane & 15), kt * 32 + (lane >> 4) * 8,
                    Wofa_swz + ((size_t)((16 + nt) * 8 + kt) * 64 + lane) * 8);
        } else if (tid < 28672) {
            const int local = tid - 20480;
            const int lane = local & 63, tt = local >> 6, kt = tt & 7, nt = tt >> 3;
            swz_one(Wout, 256, nt * 16 + (lane & 15), kt * 32 + (lane >> 4) * 8,
                    Wout_swz + ((size_t)(nt * 8 + kt) * 64 + lane) * 8);
        }
    } else {
        const size_t e = ((size_t)(b - 112) * 256 + t) * 8;
        const float4 lo = *(const float4*)(inflat + e);
        const float4 hi = *(const float4*)(inflat + e + 4);
        f16x8 o;
        o[0] = (_Float16)lo.x; o[1] = (_Float16)lo.y; o[2] = (_Float16)lo.z; o[3] = (_Float16)lo.w;
        o[4] = (_Float16)hi.x; o[5] = (_Float16)hi.y; o[6] = (_Float16)hi.z; o[7] = (_Float16)hi.w;
        *(f16x8*)(inflat_h + e) = o;
    }
}

// ---------------- value GEMM: 64x64 tile, head-major C ----------------
__global__ __launch_bounds__(256) void gemm_value(const _Float16* __restrict__ A,
                                                  const _Float16* __restrict__ Wswz,
                                                  const float* __restrict__ bias,
                                                  _Float16* __restrict__ C) {
    const int mb = (blockIdx.x % 170) * 64;
    const int nb = (blockIdx.x / 170) * 64;
    const int M = NB * LEN_IN;
    const int lane = threadIdx.x & 63;
    const int w = threadIdx.x >> 6;
    const int wm = w & 1, wn = w >> 1;
    const int m0 = mb + wm * 32;
    const int n0 = nb + wn * 32;
    const int r = lane & 15;
    const int klane = (lane >> 4) * 8;
    const int rc0 = min(m0 + r, M - 1);
    const int rc1 = min(m0 + 16 + r, M - 1);
    const int ntile0 = n0 >> 4;

    f32x4 acc[2][2] = {};
    #pragma unroll
    for (int kt = 0; kt < 8; ++kt) {
        const f16x8 a0 = *(const f16x8*)(A + (size_t)rc0 * 256 + kt * 32 + klane);
        const f16x8 a1 = *(const f16x8*)(A + (size_t)rc1 * 256 + kt * 32 + klane);
        const f16x8 b0 = *(const f16x8*)(Wswz + ((size_t)((ntile0 + 0) * 8 + kt) * 64 + lane) * 8);
        const f16x8 b1 = *(const f16x8*)(Wswz + ((size_t)((ntile0 + 1) * 8 + kt) * 64 + lane) * 8);
        acc[0][0] = __builtin_amdgcn_mfma_f32_16x16x32_f16(a0, b0, acc[0][0], 0, 0, 0);
        acc[0][1] = __builtin_amdgcn_mfma_f32_16x16x32_f16(a0, b1, acc[0][1], 0, 0, 0);
        acc[1][0] = __builtin_amdgcn_mfma_f32_16x16x32_f16(a1, b0, acc[1][0], 0, 0, 0);
        acc[1][1] = __builtin_amdgcn_mfma_f32_16x16x32_f16(a1, b1, acc[1][1], 0, 0, 0);
    }
    #pragma unroll
    for (int j = 0; j < 2; ++j) {
        const int col = n0 + j * 16 + r;
        const float bb = bias[col];
        #pragma unroll
        for (int i = 0; i < 2; ++i) {
            #pragma unroll
            for (int rr = 0; rr < 4; ++rr) {
                const int row = m0 + i * 16 + (lane >> 4) * 4 + rr;
                if (row < M) {
                    // head-major value: [n][h][pix][32]
                    const int n_img = row >= LEN_IN;
                    const int pix = row - (n_img ? LEN_IN : 0);
                    C[((((size_t)(n_img * 8 + (col >> 5)) * LEN_IN) + pix) << 5)
                      + (col & 31)] = (_Float16)(acc[i][j][rr] + bb);
                }
            }
        }
    }
}

// ------- sample_out: ofa GEMM + softmax + tasks + gather + out-proj --------
__device__ __forceinline__ f16x8 sp8(_Float16 w) {
    return (f16x8){w, w, w, w, w, w, w, w};
}

__global__ __launch_bounds__(512) void sample_out(const float* __restrict__ query,
                                                  const float* __restrict__ refp,
                                                  const _Float16* __restrict__ Wofa_swz,
                                                  const float* __restrict__ b_off,
                                                  const float* __restrict__ b_attn,
                                                  const _Float16* __restrict__ value,
                                                  const _Float16* __restrict__ Wout_swz,
                                                  const float* __restrict__ b_out,
                                                  float* __restrict__ out) {
    __shared__ _Float16 ofa_s[16][OFA_PAD];                // 12.25 KB (aliased by oplds)
    __shared__ float refs[16][NLEV][2];                    // 0.5 KB
    __shared__ uint4 tasks[2048];                          // 32 KB
    uint4* oplds = (uint4*)&ofa_s[0][0];                   // 8 KB alias (ofa dead post-task)

    const int t = threadIdx.x;
    // XCD-aware partition (empirical bid%8 = XCD): XCD 0..3 -> image 0,
    // XCD 4..7 -> image 1; each XCD's L2 caches one 2.79 MB value table.
    const int xcd = blockIdx.x & 7;
    const int slot = blockIdx.x >> 3;
    const int n = xcd >> 2;
    const int grp = slot * 4 + (xcd & 3);
    if (grp >= NQ / 16) return;            // block-uniform early exit
    const int q0 = grp * 16;
    const size_t qb = (size_t)n * NQ + q0;

    // ---- phase 0: in-block ofa GEMM: [16 x 384] = query[16x256] @ Wofa ----
    {
        const int lane = t & 63;
        const int w = t >> 6;              // 0..7, wave w -> ntiles 3w..3w+2
        const int r = lane & 15;
        const int klane = (lane >> 4) * 8;
        const float* qrow = query + (qb + r) * 256 + klane;
        f32x4 acc[3] = {};
        #pragma unroll
        for (int kt = 0; kt < 8; ++kt) {
            const float4 lo = *(const float4*)(qrow + kt * 32);
            const float4 hi = *(const float4*)(qrow + kt * 32 + 4);
            f16x8 a;
            a[0] = (_Float16)lo.x; a[1] = (_Float16)lo.y; a[2] = (_Float16)lo.z; a[3] = (_Float16)lo.w;
            a[4] = (_Float16)hi.x; a[5] = (_Float16)hi.y; a[6] = (_Float16)hi.z; a[7] = (_Float16)hi.w;
            #pragma unroll
            for (int nt = 0; nt < 3; ++nt) {
                const int ntile = w * 3 + nt;
                const f16x8 b = *(const f16x8*)(Wofa_swz + ((size_t)(ntile * 8 + kt) * 64 + lane) * 8);
                acc[nt] = __builtin_amdgcn_mfma_f32_16x16x32_f16(a, b, acc[nt], 0, 0, 0);
            }
        }
        #pragma unroll
        for (int nt = 0; nt < 3; ++nt) {
            const int col = (w * 3 + nt) * 16 + r;
            const float bb = (col < 256) ? b_off[col] : b_attn[col - 256];
            #pragma unroll
            for (int rr = 0; rr < 4; ++rr) {
                const int q = (lane >> 4) * 4 + rr;
                ofa_s[q][col] = (_Float16)(acc[nt][rr] + bb);
            }
        }
    }
    __syncthreads();

    // ---- phase 1: refs + softmax (threads 0..127); probs written back fp16 ----
    if (t < 128) {
        {
            const int i = t >> 3, rem = t & 7;
            refs[i][rem >> 1][rem & 1] = refp[(qb + i) * NLEV * 2 + rem];
        }
        const int q = t >> 3, h = t & 7;
        _Float16* arow = &ofa_s[q][256 + h * 16];
        float a[16];
        #pragma unroll
        for (int j = 0; j < 16; ++j) a[j] = (float)arow[j];
        float m = a[0];
        #pragma unroll
        for (int j = 1; j < 16; ++j) m = fmaxf(m, a[j]);
        float s = 0.f;
        #pragma unroll
        for (int j = 0; j < 16; ++j) { const float e = __expf(a[j] - m); a[j] = e; s += e; }
        const float inv = 1.0f / s;
        #pragma unroll
        for (int j = 0; j < 16; ++j) arow[j] = (_Float16)(a[j] * inv);
    }
    __syncthreads();

    // ---- phase 2: task precompute: 512 threads -> (q, h, lvl), 4 pts each ----
    {
        const int q = t >> 5, h = (t >> 2) & 7, lvl = t & 3, qh = t >> 2;
        constexpr int HS[4] = {64, 32, 16, 8};
        constexpr int ST[4] = {0, 4096, 5120, 5376};
        const int H_ = HS[lvl], W_ = HS[lvl], st = ST[lvl];
        const float fW = (float)W_, fH = (float)H_;
        const float invW = 1.0f / fW, invH = 1.0f / fH;
        const float rx = refs[q][lvl][0];
        const float ry = refs[q][lvl][1];
        const f16x8 off8 = *(const f16x8*)&ofa_s[q][(h * 16 + lvl * 4) * 2];
        const f16x4 at4 = *(const f16x4*)&ofa_s[q][256 + h * 16 + lvl * 4];
        #pragma unroll
        for (int pt = 0; pt < NPTS; ++pt) {
            const float lx = rx + (float)off8[pt * 2]     * invW;
            const float ly = ry + (float)off8[pt * 2 + 1] * invH;
            const float aw = (float)at4[pt];
            const float x = lx * fW - 0.5f;
            const float y = ly * fH - 0.5f;
            const float x0f = floorf(x);
            const float y0f = floorf(y);
            const float wx = x - x0f;
            const float wy = y - y0f;
            const int x0 = (int)x0f, y0 = (int)y0f;
            const int x1 = x0 + 1, y1 = y0 + 1;
            const int xc0 = min(max(x0, 0), W_ - 1);
            const int xc1 = min(max(x1, 0), W_ - 1);
            const int yc0 = min(max(y0, 0), H_ - 1);
            const int yc1 = min(max(y1, 0), H_ - 1);
            const bool vx0 = (x0 >= 0) & (x0 < W_);
            const bool vx1 = (x1 >= 0) & (x1 < W_);
            const bool vy0 = (y0 >= 0) & (y0 < H_);
            const bool vy1 = (y1 >= 0) & (y1 < H_);
            const float w00 = (vx0 & vy0) ? aw * (1.f - wx) * (1.f - wy) : 0.f;
            const float w01 = (vx1 & vy0) ? aw * wx         * (1.f - wy) : 0.f;
            const float w10 = (vx0 & vy1) ? aw * (1.f - wx) * wy         : 0.f;
            const float w11 = (vx1 & vy1) ? aw * wx         * wy         : 0.f;
            TaskU tu;
            tu.s.w = (f16x4){(_Float16)w00, (_Float16)w01, (_Float16)w10, (_Float16)w11};
            tu.s.p = (u16x4){(unsigned short)(st + yc0 * W_ + xc0),
                             (unsigned short)(st + yc0 * W_ + xc1),
                             (unsigned short)(st + yc1 * W_ + xc0),
                             (unsigned short)(st + yc1 * W_ + xc1)};
            tasks[qh * 16 + ((lvl * 4 + pt) ^ (qh & 15))] = tu.u;
        }
    }
    __syncthreads();

    // ---- phase 3: gather: 512 threads -> (q, h, g); 8 ch each -> oplds ----
    {
        const int q = t >> 5, h = (t >> 2) & 7, g = t & 3, qh = t >> 2;
        const _Float16* vhead = value + ((size_t)(n * 8 + h) * LEN_IN) * 32 + g * 8;
        f16x8 acc = {};
        #pragma unroll 4
        for (int ptIdx = 0; ptIdx < 16; ++ptIdx) {
            TaskU tu;
            tu.u = tasks[qh * 16 + (ptIdx ^ (qh & 15))];
            const f16x8 v0 = *(const f16x8*)(vhead + ((size_t)tu.s.p[0] << 5));
            const f16x8 v1 = *(const f16x8*)(vhead + ((size_t)tu.s.p[1] << 5));
            const f16x8 v2 = *(const f16x8*)(vhead + ((size_t)tu.s.p[2] << 5));
            const f16x8 v3 = *(const f16x8*)(vhead + ((size_t)tu.s.p[3] << 5));
            acc += v0 * sp8(tu.s.w[0]);
            acc += v1 * sp8(tu.s.w[1]);
            acc += v2 * sp8(tu.s.w[2]);
            acc += v3 * sp8(tu.s.w[3]);
        }
        // XOR-swizzled oplds store (matches out-proj A-frag read pattern)
        const int byte = q * 512 + ((h * 64 + g * 16) ^ ((q & 7) << 4));
        *(f16x8*)((char*)oplds + byte) = acc;
    }
    __syncthreads();

    // ---- phase 4: output projection: 16 rows x 256; wave w -> ntiles 2w,2w+1
    {
        const int lane = t & 63;
        const int w = t >> 6;
        const int r = lane & 15;
        const int kq = lane >> 4;
        f32x4 acc[2] = {};
        #pragma unroll
        for (int kt = 0; kt < 8; ++kt) {
            const int abyte = r * 512 + ((kt * 64 + kq * 16) ^ ((r & 7) << 4));
            const f16x8 a = *(const f16x8*)((const char*)oplds + abyte);
            #pragma unroll
            for (int nt = 0; nt < 2; ++nt) {
                const int ntile = w * 2 + nt;
                const f16x8 b = *(const f16x8*)(Wout_swz + ((size_t)(ntile * 8 + kt) * 64 + lane) * 8);
                acc[nt] = __builtin_amdgcn_mfma_f32_16x16x32_f16(a, b, acc[nt], 0, 0, 0);
            }
        }
        #pragma unroll
        for (int nt = 0; nt < 2; ++nt) {
            const int col = (w * 2 + nt) * 16 + r;
            const float bb = b_out[col];
            #pragma unroll
            for (int rr = 0; rr < 4; ++rr) {
                const int row = kq * 4 + rr;
                out[(qb + row) * 256 + col] = acc[nt][rr] + bb;
            }
        }
    }
}

extern "C" void kernel_launch(void* const* d_in, const int* in_sizes, int n_in,
                              void* d_out, int out_size, void* d_ws, size_t ws_size,
                              hipStream_t stream) {
    const float* query  = (const float*)d_in[0];
    const float* refp   = (const float*)d_in[1];
    const float* inflat = (const float*)d_in[2];
    const float* W_value = (const float*)d_in[5];
    const float* b_value = (const float*)d_in[6];
    const float* W_off   = (const float*)d_in[7];
    const float* b_off   = (const float*)d_in[8];
    const float* W_attn  = (const float*)d_in[9];
    const float* b_attn  = (const float*)d_in[10];
    const float* W_out   = (const float*)d_in[11];
    const float* b_out   = (const float*)d_in[12];
    float* out = (float*)d_out;

    // ws layout (bytes), same proven weight offsets as R2-R9:
    //   value_h   @ 0          : 5,570,560   (head-major [n][h][pix][32])
    //   Wv_swz    @ 20,930,560 : 131,072
    //   Wofa_swz  @ 21,061,632 : 196,608
    //   Wout_swz  @ 31,170,560 : 131,072   (ends 31,301,632)
    // d_out scratch (dead before sample_out writes out; stream-ordered):
    //   inflat_h  @ d_out + 0  : 5,570,560
    char* ws = (char*)d_ws;
    _Float16* value_h   = (_Float16*)(ws);
    _Float16* Wv_swz    = (_Float16*)(ws + 20930560);
    _Float16* Wofa_swz  = (_Float16*)(ws + 21061632);
    _Float16* Wout_swz  = (_Float16*)(ws + 31170560);
    _Float16* inflat_h  = (_Float16*)((char*)d_out);

    // weights swizzle (112 blocks) + inflat cvt (1360 blocks)
    prep<<<1472, 256, 0, stream>>>(W_value, W_off, W_attn, W_out, inflat,
                                   Wv_swz, Wofa_swz, Wout_swz, inflat_h);
    // value projection only: 170x4 = 680 tile blocks
    gemm_value<<<680, 256, 0, stream>>>(inflat_h, Wv_swz, b_value, value_h);
    // ofa GEMM + softmax + tasks + gather + out-proj (writes final out)
    sample_out<<<1280, 512, 0, stream>>>(query, refp, Wofa_swz, b_off, b_attn,
                                         value_h, Wout_swz, b_out, out);
}

// Round 12
// 79.353 us; speedup vs baseline: 1.0176x; 1.0176x over previous
//
#include <hip/hip_runtime.h>

// MSDeformAttn — round 11: R8 structure (best known, 77.3) + sample_out
// occupancy push: f16 attn probs (4KB), oplds aliases tasks via double
// barrier (LDS 37.4KB), launch_bounds(512,8) -> 4 blocks/CU.
#define NB 2
#define NQ 10000
#define DM 256
#define NHEADS 8
#define NLEV 4
#define NPTS 4
#define DHEAD 32
#define LEN_IN 5440   // 64*64 + 32*32 + 16*16 + 8*8

typedef _Float16 f16x8 __attribute__((ext_vector_type(8)));
typedef _Float16 f16x4 __attribute__((ext_vector_type(4)));
typedef float    f32x4 __attribute__((ext_vector_type(4)));
typedef unsigned short u16x4 __attribute__((ext_vector_type(4)));

union TaskU {
    struct { f16x4 w; u16x4 p; } s;
    uint4 u;
};

// ---------------- prep: weight swizzle + fp32->fp16 cvt of query/inflat ----
__device__ __forceinline__ void swz_one(const float* __restrict__ W, int Nw,
                                        int srcCol, int kbase,
                                        _Float16* __restrict__ dst) {
    f16x8 v;
    #pragma unroll
    for (int j = 0; j < 8; ++j) v[j] = (_Float16)W[(size_t)(kbase + j) * Nw + srcCol];
    *(f16x8*)dst = v;
}

__global__ __launch_bounds__(256) void prep(const float* __restrict__ Wv,
                                            const float* __restrict__ Wo,
                                            const float* __restrict__ Wa,
                                            const float* __restrict__ Wout,
                                            const float* __restrict__ query,
                                            const float* __restrict__ inflat,
                                            _Float16* __restrict__ Wv_swz,
                                            _Float16* __restrict__ Wofa_swz,
                                            _Float16* __restrict__ Wout_swz,
                                            _Float16* __restrict__ query_h,
                                            _Float16* __restrict__ inflat_h) {
    const int b = blockIdx.x;
    const int t = threadIdx.x;
    if (b < 112) {
        const int tid = b * 256 + t;
        if (tid < 8192) {
            const int lane = tid & 63, tt = tid >> 6, kt = tt & 7, nt = tt >> 3;
            swz_one(Wv, 256, nt * 16 + (lane & 15), kt * 32 + (lane >> 4) * 8,
                    Wv_swz + ((size_t)(nt * 8 + kt) * 64 + lane) * 8);
        } else if (tid < 16384) {
            const int local = tid - 8192;
            const int lane = local & 63, tt = local >> 6, kt = tt & 7, nt = tt >> 3;
            swz_one(Wo, 256, nt * 16 + (lane & 15), kt * 32 + (lane >> 4) * 8,
                    Wofa_swz + ((size_t)(nt * 8 + kt) * 64 + lane) * 8);
        } else if (tid < 20480) {
            const int local = tid - 16384;
            const int lane = local & 63, tt = local >> 6, kt = tt & 7, nt = tt >> 3;
            swz_one(Wa, 128, nt * 16 + (lane & 15), kt * 32 + (lane >> 4) * 8,
                    Wofa_swz + ((size_t)((16 + nt) * 8 + kt) * 64 + lane) * 8);
        } else if (tid < 28672) {
            const int local = tid - 20480;
            const int lane = local & 63, tt = local >> 6, kt = tt & 7, nt = tt >> 3;
            swz_one(Wout, 256, nt * 16 + (lane & 15), kt * 32 + (lane >> 4) * 8,
                    Wout_swz + ((size_t)(nt * 8 + kt) * 64 + lane) * 8);
        }
    } else if (b < 112 + 2500) {
        const size_t e = ((size_t)(b - 112) * 256 + t) * 8;
        const float4 lo = *(const float4*)(query + e);
        const float4 hi = *(const float4*)(query + e + 4);
        f16x8 o;
        o[0] = (_Float16)lo.x; o[1] = (_Float16)lo.y; o[2] = (_Float16)lo.z; o[3] = (_Float16)lo.w;
        o[4] = (_Float16)hi.x; o[5] = (_Float16)hi.y; o[6] = (_Float16)hi.z; o[7] = (_Float16)hi.w;
        *(f16x8*)(query_h + e) = o;
    } else {
        const size_t e = ((size_t)(b - 2612) * 256 + t) * 8;
        const float4 lo = *(const float4*)(inflat + e);
        const float4 hi = *(const float4*)(inflat + e + 4);
        f16x8 o;
        o[0] = (_Float16)lo.x; o[1] = (_Float16)lo.y; o[2] = (_Float16)lo.z; o[3] = (_Float16)lo.w;
        o[4] = (_Float16)hi.x; o[5] = (_Float16)hi.y; o[6] = (_Float16)hi.z; o[7] = (_Float16)hi.w;
        *(f16x8*)(inflat_h + e) = o;
    }
}

// ---------------- 64x64 tile GEMM body ----------------
// OUTMODE: 0 = fp16 row-major, 2 = fp16 head-major value
template<int OUTMODE>
__device__ __forceinline__ void tile_gemm(const _Float16* __restrict__ A,
                                          const _Float16* __restrict__ Wswz,
                                          const float* __restrict__ bias0,
                                          const float* __restrict__ bias1,
                                          int bsplit,
                                          void* __restrict__ C_,
                                          int M, int N, int mb, int nb) {
    const int lane = threadIdx.x & 63;
    const int w = threadIdx.x >> 6;
    const int wm = w & 1, wn = w >> 1;
    const int m0 = mb + wm * 32;
    const int n0 = nb + wn * 32;
    const int r = lane & 15;
    const int klane = (lane >> 4) * 8;
    const int rc0 = min(m0 + r, M - 1);
    const int rc1 = min(m0 + 16 + r, M - 1);
    const int ntile0 = n0 >> 4;

    f32x4 acc[2][2] = {};
    #pragma unroll
    for (int kt = 0; kt < 8; ++kt) {
        const f16x8 a0 = *(const f16x8*)(A + (size_t)rc0 * 256 + kt * 32 + klane);
        const f16x8 a1 = *(const f16x8*)(A + (size_t)rc1 * 256 + kt * 32 + klane);
        const f16x8 b0 = *(const f16x8*)(Wswz + ((size_t)((ntile0 + 0) * 8 + kt) * 64 + lane) * 8);
        const f16x8 b1 = *(const f16x8*)(Wswz + ((size_t)((ntile0 + 1) * 8 + kt) * 64 + lane) * 8);
        acc[0][0] = __builtin_amdgcn_mfma_f32_16x16x32_f16(a0, b0, acc[0][0], 0, 0, 0);
        acc[0][1] = __builtin_amdgcn_mfma_f32_16x16x32_f16(a0, b1, acc[0][1], 0, 0, 0);
        acc[1][0] = __builtin_amdgcn_mfma_f32_16x16x32_f16(a1, b0, acc[1][0], 0, 0, 0);
        acc[1][1] = __builtin_amdgcn_mfma_f32_16x16x32_f16(a1, b1, acc[1][1], 0, 0, 0);
    }
    #pragma unroll
    for (int j = 0; j < 2; ++j) {
        const int col = n0 + j * 16 + r;
        const float bb = (col < bsplit) ? bias0[col] : bias1[col - bsplit];
        #pragma unroll
        for (int i = 0; i < 2; ++i) {
            #pragma unroll
            for (int rr = 0; rr < 4; ++rr) {
                const int row = m0 + i * 16 + (lane >> 4) * 4 + rr;
                if (row < M) {
                    const float v = acc[i][j][rr] + bb;
                    if constexpr (OUTMODE == 0) {
                        ((_Float16*)C_)[(size_t)row * N + col] = (_Float16)v;
                    } else {
                        // head-major value: [n][h][pix][32]
                        const int n_img = row >= LEN_IN;
                        const int pix = row - (n_img ? LEN_IN : 0);
                        ((_Float16*)C_)[((((size_t)(n_img * 8 + (col >> 5)) * LEN_IN) + pix) << 5)
                                        + (col & 31)] = (_Float16)v;
                    }
                }
            }
        }
    }
}

// Fused front GEMMs: blocks 0..679 value-proj (170x4), 680..2557 ofa (313x6).
__global__ __launch_bounds__(256) void gemm_front(const _Float16* __restrict__ inflat_h,
                                                  const _Float16* __restrict__ query_h,
                                                  const _Float16* __restrict__ Wv_swz,
                                                  const _Float16* __restrict__ Wofa_swz,
                                                  const float* __restrict__ b_value,
                                                  const float* __restrict__ b_off,
                                                  const float* __restrict__ b_attn,
                                                  _Float16* __restrict__ value_h,
                                                  _Float16* __restrict__ ofa_h) {
    const int bx = blockIdx.x;
    if (bx < 680) {
        tile_gemm<2>(inflat_h, Wv_swz, b_value, b_value, 256, value_h,
                     NB * LEN_IN, 256, (bx % 170) * 64, (bx / 170) * 64);
    } else {
        const int b2 = bx - 680;
        tile_gemm<0>(query_h, Wofa_swz, b_off, b_attn, 256, ofa_h,
                     NB * NQ, 384, (b2 % 313) * 64, (b2 / 313) * 64);
    }
}

// ------- sample_out: softmax + tasks + gather + fused output projection ----
__device__ __forceinline__ f16x8 sp8(_Float16 w) {
    return (f16x8){w, w, w, w, w, w, w, w};
}

__global__ __launch_bounds__(512, 8) void sample_out(const float* __restrict__ refp,
                                                     const _Float16* __restrict__ ofa,
                                                     const _Float16* __restrict__ value,
                                                     const _Float16* __restrict__ Wout_swz,
                                                     const float* __restrict__ b_out,
                                                     float* __restrict__ out) {
    __shared__ _Float16 attns_s[16][128];                   // 4 KB (f16 probs)
    __shared__ float refs[16][NLEV][2];                     // 0.5 KB
    __shared__ uint4 tasks[2048];                           // 32 KB
    // oplds aliases tasks[0:512] (8 KB): valid because gather finishes ALL
    // task reads before the barrier that precedes oplds writes.
    uint4* oplds = tasks;

    const int t = threadIdx.x;
    // XCD-aware partition (empirical bid%8 = XCD): XCD 0..3 -> image 0,
    // XCD 4..7 -> image 1; each XCD's L2 caches one 2.79 MB value table.
    const int xcd = blockIdx.x & 7;
    const int slot = blockIdx.x >> 3;
    const int n = xcd >> 2;
    const int grp = slot * 4 + (xcd & 3);
    if (grp >= NQ / 16) return;            // block-uniform early exit
    const int q0 = grp * 16;
    const size_t qb = (size_t)n * NQ + q0;

    // ---- refs + softmax for 16 queries (threads 0..127); probs stored f16 ----
    if (t < 128) {
        {
            const int i = t >> 3, rem = t & 7;
            refs[i][rem >> 1][rem & 1] = refp[(qb + i) * NLEV * 2 + rem];
        }
        const int q = t >> 3, h = t & 7;
        const _Float16* arow = ofa + (qb + q) * 384 + 256 + h * 16;
        const f16x8 a0 = *(const f16x8*)arow;
        const f16x8 a1 = *(const f16x8*)(arow + 8);
        float a[16];
        #pragma unroll
        for (int j = 0; j < 8; ++j) { a[j] = (float)a0[j]; a[8 + j] = (float)a1[j]; }
        float m = a[0];
        #pragma unroll
        for (int j = 1; j < 16; ++j) m = fmaxf(m, a[j]);
        float s = 0.f;
        #pragma unroll
        for (int j = 0; j < 16; ++j) { const float e = __expf(a[j] - m); a[j] = e; s += e; }
        const float inv = 1.0f / s;
        #pragma unroll
        for (int j = 0; j < 16; ++j) attns_s[q][h * 16 + j] = (_Float16)(a[j] * inv);
    }
    __syncthreads();

    // ---- task phase: 512 threads -> (q, h, lvl), 4 pts each ----
    {
        const int q = t >> 5, h = (t >> 2) & 7, lvl = t & 3, qh = t >> 2;
        constexpr int HS[4] = {64, 32, 16, 8};
        constexpr int ST[4] = {0, 4096, 5120, 5376};
        const int H_ = HS[lvl], W_ = HS[lvl], st = ST[lvl];
        const float fW = (float)W_, fH = (float)H_;
        const float invW = 1.0f / fW, invH = 1.0f / fH;
        const float rx = refs[q][lvl][0];
        const float ry = refs[q][lvl][1];
        const f16x8 off8 = *(const f16x8*)(ofa + (qb + q) * 384 + (h * 16 + lvl * 4) * 2);
        const f16x4 at4 = *(const f16x4*)&attns_s[q][h * 16 + lvl * 4];
        #pragma unroll
        for (int pt = 0; pt < NPTS; ++pt) {
            const float lx = rx + (float)off8[pt * 2]     * invW;
            const float ly = ry + (float)off8[pt * 2 + 1] * invH;
            const float aw = (float)at4[pt];
            const float x = lx * fW - 0.5f;
            const float y = ly * fH - 0.5f;
            const float x0f = floorf(x);
            const float y0f = floorf(y);
            const float wx = x - x0f;
            const float wy = y - y0f;
            const int x0 = (int)x0f, y0 = (int)y0f;
            const int x1 = x0 + 1, y1 = y0 + 1;
            const int xc0 = min(max(x0, 0), W_ - 1);
            const int xc1 = min(max(x1, 0), W_ - 1);
            const int yc0 = min(max(y0, 0), H_ - 1);
            const int yc1 = min(max(y1, 0), H_ - 1);
            const bool vx0 = (x0 >= 0) & (x0 < W_);
            const bool vx1 = (x1 >= 0) & (x1 < W_);
            const bool vy0 = (y0 >= 0) & (y0 < H_);
            const bool vy1 = (y1 >= 0) & (y1 < H_);
            const float w00 = (vx0 & vy0) ? aw * (1.f - wx) * (1.f - wy) : 0.f;
            const float w01 = (vx1 & vy0) ? aw * wx         * (1.f - wy) : 0.f;
            const float w10 = (vx0 & vy1) ? aw * (1.f - wx) * wy         : 0.f;
            const float w11 = (vx1 & vy1) ? aw * wx         * wy         : 0.f;
            TaskU tu;
            tu.s.w = (f16x4){(_Float16)w00, (_Float16)w01, (_Float16)w10, (_Float16)w11};
            tu.s.p = (u16x4){(unsigned short)(st + yc0 * W_ + xc0),
                             (unsigned short)(st + yc0 * W_ + xc1),
                             (unsigned short)(st + yc1 * W_ + xc0),
                             (unsigned short)(st + yc1 * W_ + xc1)};
            tasks[qh * 16 + ((lvl * 4 + pt) ^ (qh & 15))] = tu.u;
        }
    }
    __syncthreads();

    // ---- gather phase: 512 threads -> (q, h, g); acc in registers ----
    f16x8 gacc = {};
    {
        const int qh = t >> 2, g = t & 3;
        const int h = qh & 7;
        const _Float16* vhead = value + ((size_t)(n * 8 + h) * LEN_IN) * 32 + g * 8;
        #pragma unroll 4
        for (int ptIdx = 0; ptIdx < 16; ++ptIdx) {
            TaskU tu;
            tu.u = tasks[qh * 16 + (ptIdx ^ (qh & 15))];
            const f16x8 v0 = *(const f16x8*)(vhead + ((size_t)tu.s.p[0] << 5));
            const f16x8 v1 = *(const f16x8*)(vhead + ((size_t)tu.s.p[1] << 5));
            const f16x8 v2 = *(const f16x8*)(vhead + ((size_t)tu.s.p[2] << 5));
            const f16x8 v3 = *(const f16x8*)(vhead + ((size_t)tu.s.p[3] << 5));
            gacc += v0 * sp8(tu.s.w[0]);
            gacc += v1 * sp8(tu.s.w[1]);
            gacc += v2 * sp8(tu.s.w[2]);
            gacc += v3 * sp8(tu.s.w[3]);
        }
    }
    __syncthreads();   // all task reads complete -> tasks region reusable

    // ---- write gather results into oplds (aliases tasks), swizzled ----
    {
        const int q = t >> 5, h = (t >> 2) & 7, g = t & 3;
        const int byte = q * 512 + ((h * 64 + g * 16) ^ ((q & 7) << 4));
        *(f16x8*)((char*)oplds + byte) = gacc;
    }
    __syncthreads();

    // ---- fused output projection: 16 rows x 256; wave w -> ntiles 2w,2w+1
    {
        const int lane = t & 63;
        const int w = t >> 6;
        const int r = lane & 15;
        const int kq = lane >> 4;
        f32x4 acc[2] = {};
        #pragma unroll
        for (int kt = 0; kt < 8; ++kt) {
            const int abyte = r * 512 + ((kt * 64 + kq * 16) ^ ((r & 7) << 4));
            const f16x8 a = *(const f16x8*)((const char*)oplds + abyte);
            #pragma unroll
            for (int nt = 0; nt < 2; ++nt) {
                const int ntile = w * 2 + nt;
                const f16x8 b = *(const f16x8*)(Wout_swz + ((size_t)(ntile * 8 + kt) * 64 + lane) * 8);
                acc[nt] = __builtin_amdgcn_mfma_f32_16x16x32_f16(a, b, acc[nt], 0, 0, 0);
            }
        }
        #pragma unroll
        for (int nt = 0; nt < 2; ++nt) {
            const int col = (w * 2 + nt) * 16 + r;
            const float bb = b_out[col];
            #pragma unroll
            for (int rr = 0; rr < 4; ++rr) {
                const int row = kq * 4 + rr;
                out[(qb + row) * 256 + col] = acc[nt][rr] + bb;
            }
        }
    }
}

extern "C" void kernel_launch(void* const* d_in, const int* in_sizes, int n_in,
                              void* d_out, int out_size, void* d_ws, size_t ws_size,
                              hipStream_t stream) {
    const float* query  = (const float*)d_in[0];
    const float* refp   = (const float*)d_in[1];
    const float* inflat = (const float*)d_in[2];
    const float* W_value = (const float*)d_in[5];
    const float* b_value = (const float*)d_in[6];
    const float* W_off   = (const float*)d_in[7];
    const float* b_off   = (const float*)d_in[8];
    const float* W_attn  = (const float*)d_in[9];
    const float* b_attn  = (const float*)d_in[10];
    const float* W_out   = (const float*)d_in[11];
    const float* b_out   = (const float*)d_in[12];
    float* out = (float*)d_out;

    // ws layout (bytes) — proven R2-R8 offsets:
    //   value_h   @ 0          : 5,570,560   (head-major [n][h][pix][32])
    //   ofa_h     @ 5,570,560  : 15,360,000  (ends 20,930,560)
    //   Wv_swz    @ 20,930,560 : 131,072
    //   Wofa_swz  @ 21,061,632 : 196,608
    //   Wout_swz  @ 31,170,560 : 131,072   (ends 31,301,632)
    // d_out used as scratch before sample_out writes it (proven R3-R8):
    //   query_h   @ d_out + 0          : 10,240,000
    //   inflat_h  @ d_out + 10,240,000 :  5,570,560
    char* ws = (char*)d_ws;
    _Float16* value_h   = (_Float16*)(ws);
    _Float16* ofa_h     = (_Float16*)(ws + 5570560);
    _Float16* Wv_swz    = (_Float16*)(ws + 20930560);
    _Float16* Wofa_swz  = (_Float16*)(ws + 21061632);
    _Float16* Wout_swz  = (_Float16*)(ws + 31170560);
    _Float16* query_h   = (_Float16*)((char*)d_out);
    _Float16* inflat_h  = (_Float16*)((char*)d_out + 10240000);

    prep<<<3972, 256, 0, stream>>>(W_value, W_off, W_attn, W_out, query, inflat,
                                   Wv_swz, Wofa_swz, Wout_swz, query_h, inflat_h);
    // fused value-proj + off/attn-proj: 680 + 1878 = 2558 tile blocks
    gemm_front<<<2558, 256, 0, stream>>>(inflat_h, query_h, Wv_swz, Wofa_swz,
                                         b_value, b_off, b_attn, value_h, ofa_h);
    // softmax + tasks + gather + fused out-projection (writes final out).
    sample_out<<<1280, 512, 0, stream>>>(refp, ofa_h, value_h, Wout_swz,
                                         b_out, out);
}

// Round 13
// 77.201 us; speedup vs baseline: 1.0460x; 1.0279x over previous
//
#include <hip/hip_runtime.h>

// MSDeformAttn — round 12: exact revert to the round-8 best (77.3 us).
// 512-thread single-pass sample_out (f32 attn probs, separate oplds buffer,
// no min-wave launch bound), XCD-aware image partition. 3 launches.
#define NB 2
#define NQ 10000
#define DM 256
#define NHEADS 8
#define NLEV 4
#define NPTS 4
#define DHEAD 32
#define LEN_IN 5440   // 64*64 + 32*32 + 16*16 + 8*8

typedef _Float16 f16x8 __attribute__((ext_vector_type(8)));
typedef _Float16 f16x4 __attribute__((ext_vector_type(4)));
typedef float    f32x4 __attribute__((ext_vector_type(4)));
typedef unsigned short u16x4 __attribute__((ext_vector_type(4)));

union TaskU {
    struct { f16x4 w; u16x4 p; } s;
    uint4 u;
};

// ---------------- prep: weight swizzle + fp32->fp16 cvt of query/inflat ----
__device__ __forceinline__ void swz_one(const float* __restrict__ W, int Nw,
                                        int srcCol, int kbase,
                                        _Float16* __restrict__ dst) {
    f16x8 v;
    #pragma unroll
    for (int j = 0; j < 8; ++j) v[j] = (_Float16)W[(size_t)(kbase + j) * Nw + srcCol];
    *(f16x8*)dst = v;
}

__global__ __launch_bounds__(256) void prep(const float* __restrict__ Wv,
                                            const float* __restrict__ Wo,
                                            const float* __restrict__ Wa,
                                            const float* __restrict__ Wout,
                                            const float* __restrict__ query,
                                            const float* __restrict__ inflat,
                                            _Float16* __restrict__ Wv_swz,
                                            _Float16* __restrict__ Wofa_swz,
                                            _Float16* __restrict__ Wout_swz,
                                            _Float16* __restrict__ query_h,
                                            _Float16* __restrict__ inflat_h) {
    const int b = blockIdx.x;
    const int t = threadIdx.x;
    if (b < 112) {
        const int tid = b * 256 + t;
        if (tid < 8192) {
            const int lane = tid & 63, tt = tid >> 6, kt = tt & 7, nt = tt >> 3;
            swz_one(Wv, 256, nt * 16 + (lane & 15), kt * 32 + (lane >> 4) * 8,
                    Wv_swz + ((size_t)(nt * 8 + kt) * 64 + lane) * 8);
        } else if (tid < 16384) {
            const int local = tid - 8192;
            const int lane = local & 63, tt = local >> 6, kt = tt & 7, nt = tt >> 3;
            swz_one(Wo, 256, nt * 16 + (lane & 15), kt * 32 + (lane >> 4) * 8,
                    Wofa_swz + ((size_t)(nt * 8 + kt) * 64 + lane) * 8);
        } else if (tid < 20480) {
            const int local = tid - 16384;
            const int lane = local & 63, tt = local >> 6, kt = tt & 7, nt = tt >> 3;
            swz_one(Wa, 128, nt * 16 + (lane & 15), kt * 32 + (lane >> 4) * 8,
                    Wofa_swz + ((size_t)((16 + nt) * 8 + kt) * 64 + lane) * 8);
        } else if (tid < 28672) {
            const int local = tid - 20480;
            const int lane = local & 63, tt = local >> 6, kt = tt & 7, nt = tt >> 3;
            swz_one(Wout, 256, nt * 16 + (lane & 15), kt * 32 + (lane >> 4) * 8,
                    Wout_swz + ((size_t)(nt * 8 + kt) * 64 + lane) * 8);
        }
    } else if (b < 112 + 2500) {
        const size_t e = ((size_t)(b - 112) * 256 + t) * 8;
        const float4 lo = *(const float4*)(query + e);
        const float4 hi = *(const float4*)(query + e + 4);
        f16x8 o;
        o[0] = (_Float16)lo.x; o[1] = (_Float16)lo.y; o[2] = (_Float16)lo.z; o[3] = (_Float16)lo.w;
        o[4] = (_Float16)hi.x; o[5] = (_Float16)hi.y; o[6] = (_Float16)hi.z; o[7] = (_Float16)hi.w;
        *(f16x8*)(query_h + e) = o;
    } else {
        const size_t e = ((size_t)(b - 2612) * 256 + t) * 8;
        const float4 lo = *(const float4*)(inflat + e);
        const float4 hi = *(const float4*)(inflat + e + 4);
        f16x8 o;
        o[0] = (_Float16)lo.x; o[1] = (_Float16)lo.y; o[2] = (_Float16)lo.z; o[3] = (_Float16)lo.w;
        o[4] = (_Float16)hi.x; o[5] = (_Float16)hi.y; o[6] = (_Float16)hi.z; o[7] = (_Float16)hi.w;
        *(f16x8*)(inflat_h + e) = o;
    }
}

// ---------------- 64x64 tile GEMM body ----------------
// OUTMODE: 0 = fp16 row-major, 2 = fp16 head-major value
template<int OUTMODE>
__device__ __forceinline__ void tile_gemm(const _Float16* __restrict__ A,
                                          const _Float16* __restrict__ Wswz,
                                          const float* __restrict__ bias0,
                                          const float* __restrict__ bias1,
                                          int bsplit,
                                          void* __restrict__ C_,
                                          int M, int N, int mb, int nb) {
    const int lane = threadIdx.x & 63;
    const int w = threadIdx.x >> 6;
    const int wm = w & 1, wn = w >> 1;
    const int m0 = mb + wm * 32;
    const int n0 = nb + wn * 32;
    const int r = lane & 15;
    const int klane = (lane >> 4) * 8;
    const int rc0 = min(m0 + r, M - 1);
    const int rc1 = min(m0 + 16 + r, M - 1);
    const int ntile0 = n0 >> 4;

    f32x4 acc[2][2] = {};
    #pragma unroll
    for (int kt = 0; kt < 8; ++kt) {
        const f16x8 a0 = *(const f16x8*)(A + (size_t)rc0 * 256 + kt * 32 + klane);
        const f16x8 a1 = *(const f16x8*)(A + (size_t)rc1 * 256 + kt * 32 + klane);
        const f16x8 b0 = *(const f16x8*)(Wswz + ((size_t)((ntile0 + 0) * 8 + kt) * 64 + lane) * 8);
        const f16x8 b1 = *(const f16x8*)(Wswz + ((size_t)((ntile0 + 1) * 8 + kt) * 64 + lane) * 8);
        acc[0][0] = __builtin_amdgcn_mfma_f32_16x16x32_f16(a0, b0, acc[0][0], 0, 0, 0);
        acc[0][1] = __builtin_amdgcn_mfma_f32_16x16x32_f16(a0, b1, acc[0][1], 0, 0, 0);
        acc[1][0] = __builtin_amdgcn_mfma_f32_16x16x32_f16(a1, b0, acc[1][0], 0, 0, 0);
        acc[1][1] = __builtin_amdgcn_mfma_f32_16x16x32_f16(a1, b1, acc[1][1], 0, 0, 0);
    }
    #pragma unroll
    for (int j = 0; j < 2; ++j) {
        const int col = n0 + j * 16 + r;
        const float bb = (col < bsplit) ? bias0[col] : bias1[col - bsplit];
        #pragma unroll
        for (int i = 0; i < 2; ++i) {
            #pragma unroll
            for (int rr = 0; rr < 4; ++rr) {
                const int row = m0 + i * 16 + (lane >> 4) * 4 + rr;
                if (row < M) {
                    const float v = acc[i][j][rr] + bb;
                    if constexpr (OUTMODE == 0) {
                        ((_Float16*)C_)[(size_t)row * N + col] = (_Float16)v;
                    } else {
                        // head-major value: [n][h][pix][32]
                        const int n_img = row >= LEN_IN;
                        const int pix = row - (n_img ? LEN_IN : 0);
                        ((_Float16*)C_)[((((size_t)(n_img * 8 + (col >> 5)) * LEN_IN) + pix) << 5)
                                        + (col & 31)] = (_Float16)v;
                    }
                }
            }
        }
    }
}

// Fused front GEMMs: blocks 0..679 value-proj (170x4), 680..2557 ofa (313x6).
__global__ __launch_bounds__(256) void gemm_front(const _Float16* __restrict__ inflat_h,
                                                  const _Float16* __restrict__ query_h,
                                                  const _Float16* __restrict__ Wv_swz,
                                                  const _Float16* __restrict__ Wofa_swz,
                                                  const float* __restrict__ b_value,
                                                  const float* __restrict__ b_off,
                                                  const float* __restrict__ b_attn,
                                                  _Float16* __restrict__ value_h,
                                                  _Float16* __restrict__ ofa_h) {
    const int bx = blockIdx.x;
    if (bx < 680) {
        tile_gemm<2>(inflat_h, Wv_swz, b_value, b_value, 256, value_h,
                     NB * LEN_IN, 256, (bx % 170) * 64, (bx / 170) * 64);
    } else {
        const int b2 = bx - 680;
        tile_gemm<0>(query_h, Wofa_swz, b_off, b_attn, 256, ofa_h,
                     NB * NQ, 384, (b2 % 313) * 64, (b2 / 313) * 64);
    }
}

// ------- sample_out: softmax + tasks + gather + fused output projection ----
// 512 threads, 16 queries/block, single gather pass, 8-wave out-projection.
__device__ __forceinline__ f16x8 sp8(_Float16 w) {
    return (f16x8){w, w, w, w, w, w, w, w};
}

__global__ __launch_bounds__(512) void sample_out(const float* __restrict__ refp,
                                                  const _Float16* __restrict__ ofa,
                                                  const _Float16* __restrict__ value,
                                                  const _Float16* __restrict__ Wout_swz,
                                                  const float* __restrict__ b_out,
                                                  float* __restrict__ out) {
    // attns_s (softmax+task phases) and oplds (gather+outproj phases) have
    // disjoint live ranges separated by a barrier -> share the same 8 KB.
    __shared__ float attns_s[16][128];                      // 8 KB (aliased below)
    __shared__ float refs[16][NLEV][2];                     // 0.5 KB
    __shared__ uint4 tasks[2048];                           // 32 KB (16 q)
    uint4* oplds = (uint4*)&attns_s[0][0];                  // 8 KB alias

    const int t = threadIdx.x;
    // XCD-aware partition (empirical bid%8 = XCD): XCD 0..3 -> image 0,
    // XCD 4..7 -> image 1; each XCD's L2 caches one 2.79 MB value table.
    const int xcd = blockIdx.x & 7;
    const int slot = blockIdx.x >> 3;
    const int n = xcd >> 2;
    const int grp = slot * 4 + (xcd & 3);
    if (grp >= NQ / 16) return;            // block-uniform early exit
    const int q0 = grp * 16;
    const size_t qb = (size_t)n * NQ + q0;

    // ---- refs + softmax for 16 queries (threads 0..127) ----
    if (t < 128) {
        {
            const int i = t >> 3, rem = t & 7;
            refs[i][rem >> 1][rem & 1] = refp[(qb + i) * NLEV * 2 + rem];
        }
        const int q = t >> 3, h = t & 7;
        const _Float16* arow = ofa + (qb + q) * 384 + 256 + h * 16;
        const f16x8 a0 = *(const f16x8*)arow;
        const f16x8 a1 = *(const f16x8*)(arow + 8);
        float a[16];
        #pragma unroll
        for (int j = 0; j < 8; ++j) { a[j] = (float)a0[j]; a[8 + j] = (float)a1[j]; }
        float m = a[0];
        #pragma unroll
        for (int j = 1; j < 16; ++j) m = fmaxf(m, a[j]);
        float s = 0.f;
        #pragma unroll
        for (int j = 0; j < 16; ++j) { const float e = __expf(a[j] - m); a[j] = e; s += e; }
        const float inv = 1.0f / s;
        #pragma unroll
        for (int j = 0; j < 16; ++j) attns_s[q][h * 16 + j] = a[j] * inv;
    }
    __syncthreads();

    // ---- task phase: 512 threads -> (q, h, lvl), 4 pts each ----
    {
        const int q = t >> 5, h = (t >> 2) & 7, lvl = t & 3, qh = t >> 2;
        constexpr int HS[4] = {64, 32, 16, 8};
        constexpr int ST[4] = {0, 4096, 5120, 5376};
        const int H_ = HS[lvl], W_ = HS[lvl], st = ST[lvl];
        const float fW = (float)W_, fH = (float)H_;
        const float invW = 1.0f / fW, invH = 1.0f / fH;
        const float rx = refs[q][lvl][0];
        const float ry = refs[q][lvl][1];
        const f16x8 off8 = *(const f16x8*)(ofa + (qb + q) * 384 + (h * 16 + lvl * 4) * 2);
        const f32x4 at4 = *(const f32x4*)&attns_s[q][h * 16 + lvl * 4];
        #pragma unroll
        for (int pt = 0; pt < NPTS; ++pt) {
            const float lx = rx + (float)off8[pt * 2]     * invW;
            const float ly = ry + (float)off8[pt * 2 + 1] * invH;
            const float aw = at4[pt];
            const float x = lx * fW - 0.5f;
            const float y = ly * fH - 0.5f;
            const float x0f = floorf(x);
            const float y0f = floorf(y);
            const float wx = x - x0f;
            const float wy = y - y0f;
            const int x0 = (int)x0f, y0 = (int)y0f;
            const int x1 = x0 + 1, y1 = y0 + 1;
            const int xc0 = min(max(x0, 0), W_ - 1);
            const int xc1 = min(max(x1, 0), W_ - 1);
            const int yc0 = min(max(y0, 0), H_ - 1);
            const int yc1 = min(max(y1, 0), H_ - 1);
            const bool vx0 = (x0 >= 0) & (x0 < W_);
            const bool vx1 = (x1 >= 0) & (x1 < W_);
            const bool vy0 = (y0 >= 0) & (y0 < H_);
            const bool vy1 = (y1 >= 0) & (y1 < H_);
            const float w00 = (vx0 & vy0) ? aw * (1.f - wx) * (1.f - wy) : 0.f;
            const float w01 = (vx1 & vy0) ? aw * wx         * (1.f - wy) : 0.f;
            const float w10 = (vx0 & vy1) ? aw * (1.f - wx) * wy         : 0.f;
            const float w11 = (vx1 & vy1) ? aw * wx         * wy         : 0.f;
            TaskU tu;
            tu.s.w = (f16x4){(_Float16)w00, (_Float16)w01, (_Float16)w10, (_Float16)w11};
            tu.s.p = (u16x4){(unsigned short)(st + yc0 * W_ + xc0),
                             (unsigned short)(st + yc0 * W_ + xc1),
                             (unsigned short)(st + yc1 * W_ + xc0),
                             (unsigned short)(st + yc1 * W_ + xc1)};
            tasks[qh * 16 + ((lvl * 4 + pt) ^ (qh & 15))] = tu.u;
        }
    }
    __syncthreads();

    // ---- gather phase: 512 threads -> (q, h, g); 8 ch each ----
    {
        const int q = t >> 5, h = (t >> 2) & 7, g = t & 3, qh = t >> 2;
        const _Float16* vhead = value + ((size_t)(n * 8 + h) * LEN_IN) * 32 + g * 8;
        f16x8 acc = {};
        #pragma unroll 4
        for (int ptIdx = 0; ptIdx < 16; ++ptIdx) {
            TaskU tu;
            tu.u = tasks[qh * 16 + (ptIdx ^ (qh & 15))];
            const f16x8 v0 = *(const f16x8*)(vhead + ((size_t)tu.s.p[0] << 5));
            const f16x8 v1 = *(const f16x8*)(vhead + ((size_t)tu.s.p[1] << 5));
            const f16x8 v2 = *(const f16x8*)(vhead + ((size_t)tu.s.p[2] << 5));
            const f16x8 v3 = *(const f16x8*)(vhead + ((size_t)tu.s.p[3] << 5));
            acc += v0 * sp8(tu.s.w[0]);
            acc += v1 * sp8(tu.s.w[1]);
            acc += v2 * sp8(tu.s.w[2]);
            acc += v3 * sp8(tu.s.w[3]);
        }
        // XOR-swizzled oplds store (out-proj A-frag ds_read pattern matches)
        const int byte = q * 512 + ((h * 64 + g * 16) ^ ((q & 7) << 4));
        *(f16x8*)((char*)oplds + byte) = acc;
    }
    __syncthreads();

    // ---- fused output projection: 16 rows x 256 cols; wave w -> ntiles 2w,2w+1
    {
        const int lane = t & 63;
        const int w = t >> 6;                  // 0..7
        const int r = lane & 15;
        const int kq = lane >> 4;              // 0..3
        f32x4 acc[2] = {};
        #pragma unroll
        for (int kt = 0; kt < 8; ++kt) {
            const int abyte = r * 512 + ((kt * 64 + kq * 16) ^ ((r & 7) << 4));
            const f16x8 a = *(const f16x8*)((const char*)oplds + abyte);
            #pragma unroll
            for (int nt = 0; nt < 2; ++nt) {
                const int ntile = w * 2 + nt;
                const f16x8 b = *(const f16x8*)(Wout_swz + ((size_t)(ntile * 8 + kt) * 64 + lane) * 8);
                acc[nt] = __builtin_amdgcn_mfma_f32_16x16x32_f16(a, b, acc[nt], 0, 0, 0);
            }
        }
        #pragma unroll
        for (int nt = 0; nt < 2; ++nt) {
            const int col = (w * 2 + nt) * 16 + r;
            const float bb = b_out[col];
            #pragma unroll
            for (int rr = 0; rr < 4; ++rr) {
                const int row = kq * 4 + rr;   // q 0..15
                out[(qb + row) * 256 + col] = acc[nt][rr] + bb;
            }
        }
    }
}

extern "C" void kernel_launch(void* const* d_in, const int* in_sizes, int n_in,
                              void* d_out, int out_size, void* d_ws, size_t ws_size,
                              hipStream_t stream) {
    const float* query  = (const float*)d_in[0];
    const float* refp   = (const float*)d_in[1];
    const float* inflat = (const float*)d_in[2];
    const float* W_value = (const float*)d_in[5];
    const float* b_value = (const float*)d_in[6];
    const float* W_off   = (const float*)d_in[7];
    const float* b_off   = (const float*)d_in[8];
    const float* W_attn  = (const float*)d_in[9];
    const float* b_attn  = (const float*)d_in[10];
    const float* W_out   = (const float*)d_in[11];
    const float* b_out   = (const float*)d_in[12];
    float* out = (float*)d_out;

    // ws layout (bytes) — same proven offsets as R2-R8:
    //   value_h   @ 0          : 5,570,560   (head-major [n][h][pix][32])
    //   ofa_h     @ 5,570,560  : 15,360,000  (ends 20,930,560)
    //   Wv_swz    @ 20,930,560 : 131,072
    //   Wofa_swz  @ 21,061,632 : 196,608
    //   Wout_swz  @ 31,170,560 : 131,072   (ends 31,301,632)
    // d_out used as scratch before sample_out writes it (proven R3-R8):
    //   query_h   @ d_out + 0          : 10,240,000
    //   inflat_h  @ d_out + 10,240,000 :  5,570,560
    char* ws = (char*)d_ws;
    _Float16* value_h   = (_Float16*)(ws);
    _Float16* ofa_h     = (_Float16*)(ws + 5570560);
    _Float16* Wv_swz    = (_Float16*)(ws + 20930560);
    _Float16* Wofa_swz  = (_Float16*)(ws + 21061632);
    _Float16* Wout_swz  = (_Float16*)(ws + 31170560);
    _Float16* query_h   = (_Float16*)((char*)d_out);
    _Float16* inflat_h  = (_Float16*)((char*)d_out + 10240000);

    prep<<<3972, 256, 0, stream>>>(W_value, W_off, W_attn, W_out, query, inflat,
                                   Wv_swz, Wofa_swz, Wout_swz, query_h, inflat_h);
    // fused value-proj + off/attn-proj: 680 + 1878 = 2558 tile blocks
    gemm_front<<<2558, 256, 0, stream>>>(inflat_h, query_h, Wv_swz, Wofa_swz,
                                         b_value, b_off, b_attn, value_h, ofa_h);
    // softmax + tasks + gather + fused out-projection (writes final out).
    // 1280 blocks = 160/XCD; XCD halves own one image each (30 pad blocks).
    sample_out<<<1280, 512, 0, stream>>>(refp, ofa_h, value_h, Wout_swz,
                                         b_out, out);
}